// Round 1
// baseline (576.581 us; speedup 1.0000x reference)
//
#include <hip/hip_runtime.h>

#define D 64

// ---------------------------------------------------------------------------
// Stage 2: edge scatter. One 64-lane wave per edge; lane = feature index.
// out[dst][lane] += h[src][lane] via fp32 global atomics; deg[dst] += 1.
// ---------------------------------------------------------------------------
__global__ __launch_bounds__(256) void gcn_scatter_kernel(
    const float* __restrict__ h,
    const int* __restrict__ esrc,
    const int* __restrict__ edst,
    float* __restrict__ outsum,
    float* __restrict__ deg,
    int E)
{
    const int lane   = threadIdx.x & 63;
    const int waveId = (blockIdx.x * blockDim.x + threadIdx.x) >> 6;
    const int nWaves = (gridDim.x * blockDim.x) >> 6;

    for (int e = waveId; e < E; e += nWaves) {
        const int s = esrc[e];           // wave-uniform broadcast load
        const int d = edst[e];
        const float v = h[(size_t)s * D + lane];   // coalesced 256B row read
        atomicAdd(&outsum[(size_t)d * D + lane], v);
        if (lane == 0) atomicAdd(&deg[d], 1.0f);
    }
}

// ---------------------------------------------------------------------------
// Stage 3: per-node finalize: mean = sum/deg; out = relu(mean @ W^T + b).
// Wave per node. Lane j keeps W[j][0..63] in registers (full unroll ->
// compile-time indices -> VGPRs, no LDS, no __syncthreads).
// deg==0 nodes output exactly 0 (matches reference: relu(0/1)=0).
// ---------------------------------------------------------------------------
__global__ __launch_bounds__(256) void gcn_finalize_kernel(
    float* __restrict__ out,
    const float* __restrict__ deg,
    const float* __restrict__ W,
    const float* __restrict__ b,
    int N)
{
    const int lane = threadIdx.x & 63;

    // W row for this lane -> 64 VGPRs (consecutive addresses; compiler
    // vectorizes to dwordx4 loads). Loaded once per thread, L2-hot.
    float w[D];
    #pragma unroll
    for (int i = 0; i < D; ++i) w[i] = W[lane * D + i];
    const float bj = b[lane];

    const int waveId = (blockIdx.x * blockDim.x + threadIdx.x) >> 6;
    const int nWaves = (gridDim.x * blockDim.x) >> 6;

    for (int row = waveId; row < N; row += nWaves) {
        const float dv = deg[row];                       // broadcast load
        const float sv = out[(size_t)row * D + lane];    // coalesced
        const float mean = sv / fmaxf(dv, 1.0f);

        float acc = bj;
        #pragma unroll
        for (int k = 0; k < D; ++k) {
            const float mk = __shfl(mean, k, 64);        // broadcast lane k
            acc += mk * w[k];
        }
        const float res = (dv > 0.0f) ? fmaxf(acc, 0.0f) : 0.0f;
        out[(size_t)row * D + lane] = res;
    }
}

// ---------------------------------------------------------------------------
// Launch. Inputs (setup_inputs order): h [N*64] f32, edge_src [E] i32,
// edge_dst [E] i32, W [64*64] f32, b [64] f32. Output: [N*64] f32.
// Workspace: deg [N] f32 (the sum accumulator lives directly in d_out).
// ---------------------------------------------------------------------------
extern "C" void kernel_launch(void* const* d_in, const int* in_sizes, int n_in,
                              void* d_out, int out_size, void* d_ws, size_t ws_size,
                              hipStream_t stream) {
    const float* h    = (const float*)d_in[0];
    const int*   esrc = (const int*)d_in[1];
    const int*   edst = (const int*)d_in[2];
    const float* W    = (const float*)d_in[3];
    const float* b    = (const float*)d_in[4];

    const int N = in_sizes[0] / D;
    const int E = in_sizes[1];

    float* out = (float*)d_out;
    float* deg = (float*)d_ws;   // N floats

    // Zero the accumulator (d_out) and deg — harness poisons with 0xAA.
    hipMemsetAsync(out, 0, (size_t)N * D * sizeof(float), stream);
    hipMemsetAsync(deg, 0, (size_t)N * sizeof(float), stream);

    // 2048 blocks x 4 waves = 8192 waves (full residency), grid-stride.
    gcn_scatter_kernel<<<2048, 256, 0, stream>>>(h, esrc, edst, out, deg, E);

    gcn_finalize_kernel<<<1024, 256, 0, stream>>>(out, deg, W, b, N);
}

// Round 2
// 453.162 us; speedup vs baseline: 1.2723x; 1.2723x over previous
//
#include <hip/hip_runtime.h>

#define D 64
#define CHUNK 1024   // elements per scan block

// ---------------------------------------------------------------------------
// 1) histogram of edge_dst -> cnt[N]
// ---------------------------------------------------------------------------
__global__ __launch_bounds__(256) void hist_kernel(
    const int* __restrict__ edst, int* __restrict__ cnt, int E)
{
    const int tid = blockIdx.x * blockDim.x + threadIdx.x;
    const int stride = gridDim.x * blockDim.x;
    for (int e = tid; e < E; e += stride)
        atomicAdd(&cnt[edst[e]], 1);
}

// ---------------------------------------------------------------------------
// 2a) per-chunk exclusive scan (CHUNK=1024 elems/block, 4/thread) + chunk sums
// ---------------------------------------------------------------------------
__global__ __launch_bounds__(256) void scan_chunks_kernel(
    const int* __restrict__ cnt, int* __restrict__ offs,
    int* __restrict__ bsums, int N)
{
    __shared__ int tmp[256];
    const int t = threadIdx.x;
    const int base = blockIdx.x * CHUNK + t * 4;

    int v0 = (base + 0 < N) ? cnt[base + 0] : 0;
    int v1 = (base + 1 < N) ? cnt[base + 1] : 0;
    int v2 = (base + 2 < N) ? cnt[base + 2] : 0;
    int v3 = (base + 3 < N) ? cnt[base + 3] : 0;
    const int s = v0 + v1 + v2 + v3;

    tmp[t] = s;
    __syncthreads();
    // Hillis-Steele inclusive scan over 256 thread sums
    for (int off = 1; off < 256; off <<= 1) {
        int x = (t >= off) ? tmp[t - off] : 0;
        __syncthreads();
        tmp[t] += x;
        __syncthreads();
    }
    int run = tmp[t] - s;  // exclusive prefix within chunk
    if (base + 0 < N) offs[base + 0] = run;  run += v0;
    if (base + 1 < N) offs[base + 1] = run;  run += v1;
    if (base + 2 < N) offs[base + 2] = run;  run += v2;
    if (base + 3 < N) offs[base + 3] = run;
    if (t == 255) bsums[blockIdx.x] = tmp[255];
}

// ---------------------------------------------------------------------------
// 2b) single-block exclusive scan of chunk sums (nb <= 256)
// ---------------------------------------------------------------------------
__global__ __launch_bounds__(256) void scan_bsums_kernel(
    int* __restrict__ bsums, int nb, int* __restrict__ offs, int N, int E)
{
    __shared__ int tmp[256];
    const int t = threadIdx.x;
    const int v = (t < nb) ? bsums[t] : 0;
    tmp[t] = v;
    __syncthreads();
    for (int off = 1; off < 256; off <<= 1) {
        int x = (t >= off) ? tmp[t - off] : 0;
        __syncthreads();
        tmp[t] += x;
        __syncthreads();
    }
    if (t < nb) bsums[t] = tmp[t] - v;   // exclusive chunk prefix
    if (t == 0) offs[N] = E;
}

// ---------------------------------------------------------------------------
// 2c) add chunk prefixes back
// ---------------------------------------------------------------------------
__global__ __launch_bounds__(256) void scan_add_kernel(
    int* __restrict__ offs, const int* __restrict__ bsums, int N)
{
    const int i = blockIdx.x * blockDim.x + threadIdx.x;
    if (i < N) offs[i] += bsums[i >> 10];
}

// ---------------------------------------------------------------------------
// 3) bin edges: csr[offs[dst] + cursor[dst]++] = src
// ---------------------------------------------------------------------------
__global__ __launch_bounds__(256) void fill_csr_kernel(
    const int* __restrict__ esrc, const int* __restrict__ edst,
    const int* __restrict__ offs, int* __restrict__ cursor,
    int* __restrict__ csr, int E)
{
    const int tid = blockIdx.x * blockDim.x + threadIdx.x;
    const int stride = gridDim.x * blockDim.x;
    for (int e = tid; e < E; e += stride) {
        const int s = esrc[e];
        const int d = edst[e];
        const int pos = offs[d] + atomicAdd(&cursor[d], 1);
        csr[pos] = s;
    }
}

// ---------------------------------------------------------------------------
// 4) fused gather-mean + GEMM + relu. Wave per node; lane = output feature.
//    Conflict-free: each wave owns its dst row. h rows are L3-resident.
// ---------------------------------------------------------------------------
__global__ __launch_bounds__(256) void gather_gemm_kernel(
    const float* __restrict__ h,
    const int* __restrict__ csr,
    const int* __restrict__ offs,
    const float* __restrict__ W,
    const float* __restrict__ b,
    float* __restrict__ out,
    int N)
{
    const int lane = threadIdx.x & 63;

    // lane j holds W[j][0..63] in VGPRs; L1-hot after first wave per CU
    float w[D];
    #pragma unroll
    for (int i = 0; i < D; ++i) w[i] = W[lane * D + i];
    const float bj = b[lane];

    const int waveId = (blockIdx.x * blockDim.x + threadIdx.x) >> 6;
    const int nWaves = (gridDim.x * blockDim.x) >> 6;

    for (int node = waveId; node < N; node += nWaves) {
        const int beg = offs[node];
        const int end = offs[node + 1];

        // two-accumulator gather for ILP (2 rows in flight)
        float sum0 = 0.f, sum1 = 0.f;
        int e = beg;
        for (; e + 1 < end; e += 2) {
            const int s0 = csr[e];
            const int s1 = csr[e + 1];
            sum0 += h[(size_t)s0 * D + lane];
            sum1 += h[(size_t)s1 * D + lane];
        }
        if (e < end) sum0 += h[(size_t)csr[e] * D + lane];
        const float sum = sum0 + sum1;

        float res = 0.f;
        if (end > beg) {                      // wave-uniform branch
            const float mean = sum / (float)(end - beg);
            float acc = bj;
            #pragma unroll
            for (int k = 0; k < D; ++k)
                acc += __shfl(mean, k, 64) * w[k];
            res = fmaxf(acc, 0.f);
        }
        out[(size_t)node * D + lane] = res;
    }
}

// ---------------------------------------------------------------------------
// Launch. ws layout (ints): cnt[N] | cursor[N] | offs[N+1] | bsums | csr[E]
// total ~7.6 MB.
// ---------------------------------------------------------------------------
extern "C" void kernel_launch(void* const* d_in, const int* in_sizes, int n_in,
                              void* d_out, int out_size, void* d_ws, size_t ws_size,
                              hipStream_t stream) {
    const float* h    = (const float*)d_in[0];
    const int*   esrc = (const int*)d_in[1];
    const int*   edst = (const int*)d_in[2];
    const float* W    = (const float*)d_in[3];
    const float* b    = (const float*)d_in[4];

    const int N = in_sizes[0] / D;
    const int E = in_sizes[1];
    const int nb = (N + CHUNK - 1) / CHUNK;   // scan chunks (98 for N=100000)

    float* out = (float*)d_out;

    int* wsI    = (int*)d_ws;
    int* cnt    = wsI;                 // [N]
    int* cursor = wsI + N;             // [N]
    int* offs   = wsI + 2 * N;         // [N+1]
    int* bsums  = wsI + 3 * N + 64;    // [nb] (padded past offs[N])
    int* csr    = wsI + 3 * N + 64 + ((nb + 63) & ~63);  // [E]

    // zero cnt+cursor (adjacent) — harness poisons ws with 0xAA
    hipMemsetAsync(cnt, 0, (size_t)2 * N * sizeof(int), stream);

    hist_kernel      <<<2048, 256, 0, stream>>>(edst, cnt, E);
    scan_chunks_kernel<<<nb,   256, 0, stream>>>(cnt, offs, bsums, N);
    scan_bsums_kernel <<<1,    256, 0, stream>>>(bsums, nb, offs, N, E);
    scan_add_kernel  <<<(N + 255) / 256, 256, 0, stream>>>(offs, bsums, N);
    fill_csr_kernel  <<<2048, 256, 0, stream>>>(esrc, edst, offs, cursor, csr, E);
    gather_gemm_kernel<<<4096, 256, 0, stream>>>(h, csr, offs, W, b, out, N);
}

// Round 4
// 360.240 us; speedup vs baseline: 1.6005x; 1.2579x over previous
//
#include <hip/hip_runtime.h>

#define D 64
#define CHUNK 1024   // elements per scan block

// ---------------------------------------------------------------------------
// float -> bf16 (RNE), packed
// ---------------------------------------------------------------------------
__device__ __forceinline__ unsigned short f2bf(float x) {
    unsigned int u = __float_as_uint(x);
    u += 0x7FFFu + ((u >> 16) & 1u);     // round-to-nearest-even
    return (unsigned short)(u >> 16);
}
__device__ __forceinline__ float bf2f(unsigned short v) {
    return __uint_as_float((unsigned int)v << 16);
}

// 0) h [N*D] f32 -> hb [N*D] bf16, float4 in / ushort4 out
__global__ __launch_bounds__(256) void cvt_kernel(
    const float4* __restrict__ h4, ushort4* __restrict__ hb4, int n4)
{
    const int tid = blockIdx.x * blockDim.x + threadIdx.x;
    const int stride = gridDim.x * blockDim.x;
    for (int i = tid; i < n4; i += stride) {
        const float4 f = h4[i];
        ushort4 o;
        o.x = f2bf(f.x); o.y = f2bf(f.y); o.z = f2bf(f.z); o.w = f2bf(f.w);
        hb4[i] = o;
    }
}

// ---------------------------------------------------------------------------
// 1) histogram of edge_dst -> cnt[N]  (int4 loads, 4 edges/thread)
// ---------------------------------------------------------------------------
__global__ __launch_bounds__(256) void hist_kernel(
    const int4* __restrict__ edst4, const int* __restrict__ edst,
    int* __restrict__ cnt, int E4, int E)
{
    const int tid = blockIdx.x * blockDim.x + threadIdx.x;
    const int stride = gridDim.x * blockDim.x;
    for (int i = tid; i < E4; i += stride) {
        const int4 v = edst4[i];
        atomicAdd(&cnt[v.x], 1);
        atomicAdd(&cnt[v.y], 1);
        atomicAdd(&cnt[v.z], 1);
        atomicAdd(&cnt[v.w], 1);
    }
    if (tid == 0)
        for (int e = E4 * 4; e < E; ++e) atomicAdd(&cnt[edst[e]], 1);
}

// ---------------------------------------------------------------------------
// 2a) per-chunk exclusive scan + chunk sums
// ---------------------------------------------------------------------------
__global__ __launch_bounds__(256) void scan_chunks_kernel(
    const int* __restrict__ cnt, int* __restrict__ offs,
    int* __restrict__ bsums, int N)
{
    __shared__ int tmp[256];
    const int t = threadIdx.x;
    const int base = blockIdx.x * CHUNK + t * 4;

    int v0 = (base + 0 < N) ? cnt[base + 0] : 0;
    int v1 = (base + 1 < N) ? cnt[base + 1] : 0;
    int v2 = (base + 2 < N) ? cnt[base + 2] : 0;
    int v3 = (base + 3 < N) ? cnt[base + 3] : 0;
    const int s = v0 + v1 + v2 + v3;

    tmp[t] = s;
    __syncthreads();
    for (int off = 1; off < 256; off <<= 1) {
        int x = (t >= off) ? tmp[t - off] : 0;
        __syncthreads();
        tmp[t] += x;
        __syncthreads();
    }
    int run = tmp[t] - s;
    if (base + 0 < N) offs[base + 0] = run;  run += v0;
    if (base + 1 < N) offs[base + 1] = run;  run += v1;
    if (base + 2 < N) offs[base + 2] = run;  run += v2;
    if (base + 3 < N) offs[base + 3] = run;
    if (t == 255) bsums[blockIdx.x] = tmp[255];
}

// 2b) single-block scan of chunk sums (nb <= 256)
__global__ __launch_bounds__(256) void scan_bsums_kernel(
    int* __restrict__ bsums, int nb, int* __restrict__ offs, int N, int E)
{
    __shared__ int tmp[256];
    const int t = threadIdx.x;
    const int v = (t < nb) ? bsums[t] : 0;
    tmp[t] = v;
    __syncthreads();
    for (int off = 1; off < 256; off <<= 1) {
        int x = (t >= off) ? tmp[t - off] : 0;
        __syncthreads();
        tmp[t] += x;
        __syncthreads();
    }
    if (t < nb) bsums[t] = tmp[t] - v;
    if (t == 0) offs[N] = E;
}

// 2c) add chunk prefixes back
__global__ __launch_bounds__(256) void scan_add_kernel(
    int* __restrict__ offs, const int* __restrict__ bsums, int N)
{
    const int i = blockIdx.x * blockDim.x + threadIdx.x;
    if (i < N) offs[i] += bsums[i >> 10];
}

// ---------------------------------------------------------------------------
// 3) bin edges: csr[offs[dst] + cursor[dst]++] = src  (int4 loads)
// ---------------------------------------------------------------------------
__global__ __launch_bounds__(256) void fill_csr_kernel(
    const int4* __restrict__ esrc4, const int4* __restrict__ edst4,
    const int* __restrict__ esrc, const int* __restrict__ edst,
    const int* __restrict__ offs, int* __restrict__ cursor,
    int* __restrict__ csr, int E4, int E)
{
    const int tid = blockIdx.x * blockDim.x + threadIdx.x;
    const int stride = gridDim.x * blockDim.x;
    for (int i = tid; i < E4; i += stride) {
        const int4 s = esrc4[i];
        const int4 d = edst4[i];
        csr[offs[d.x] + atomicAdd(&cursor[d.x], 1)] = s.x;
        csr[offs[d.y] + atomicAdd(&cursor[d.y], 1)] = s.y;
        csr[offs[d.z] + atomicAdd(&cursor[d.z], 1)] = s.z;
        csr[offs[d.w] + atomicAdd(&cursor[d.w], 1)] = s.w;
    }
    if (tid == 0)
        for (int e = E4 * 4; e < E; ++e)
            csr[offs[edst[e]] + atomicAdd(&cursor[edst[e]], 1)] = esrc[e];
}

// ---------------------------------------------------------------------------
// 4) fused gather-mean + GEMM + relu.
//    Wave = 4 groups x 16 lanes. Each group reads one full row per load
//    (16 lanes x 8B bf16x4 = 128B, or x float4 = 256B on fp32 fallback).
//    2-deep unroll -> 8 rows in flight per wave. Cross-group shfl_xor
//    reduce, then register-held-W shuffle GEMM. Lane owns out feature lane.
// ---------------------------------------------------------------------------
template <bool BF16>
__global__ __launch_bounds__(256) void gather_gemm_kernel(
    const void* __restrict__ hsrc,
    const int* __restrict__ csr,
    const int* __restrict__ offs,
    const float* __restrict__ W,
    const float* __restrict__ b,
    float* __restrict__ out,
    int N)
{
    const int lane = threadIdx.x & 63;
    const int g    = lane >> 4;     // edge group 0..3
    const int gl   = lane & 15;     // owns features 4*gl .. 4*gl+3

    float w[D];
    #pragma unroll
    for (int i = 0; i < D; ++i) w[i] = W[lane * D + i];
    const float bj = b[lane];

    const unsigned short* __restrict__ hb = (const unsigned short*)hsrc;
    const float*          __restrict__ hf = (const float*)hsrc;

    auto loadrow = [&](int s, float& x0, float& x1, float& x2, float& x3) {
        if constexpr (BF16) {
            const ushort4 v = *(const ushort4*)(hb + (size_t)s * D + gl * 4);
            x0 = bf2f(v.x); x1 = bf2f(v.y); x2 = bf2f(v.z); x3 = bf2f(v.w);
        } else {
            const float4 v = *(const float4*)(hf + (size_t)s * D + gl * 4);
            x0 = v.x; x1 = v.y; x2 = v.z; x3 = v.w;
        }
    };

    const int waveId = (blockIdx.x * blockDim.x + threadIdx.x) >> 6;
    const int nWaves = (gridDim.x * blockDim.x) >> 6;

    for (int node = waveId; node < N; node += nWaves) {
        const int beg = offs[node];
        const int end = offs[node + 1];

        float a0 = 0.f, a1 = 0.f, a2 = 0.f, a3 = 0.f;
        float c0 = 0.f, c1 = 0.f, c2 = 0.f, c3 = 0.f;
        int e = beg;
        for (; e + 8 <= end; e += 8) {           // 8 rows in flight
            const int s0 = csr[e + g];
            const int s1 = csr[e + 4 + g];
            float x0, x1, x2, x3, y0, y1, y2, y3;
            loadrow(s0, x0, x1, x2, x3);
            loadrow(s1, y0, y1, y2, y3);
            a0 += x0; a1 += x1; a2 += x2; a3 += x3;
            c0 += y0; c1 += y1; c2 += y2; c3 += y3;
        }
        if (e + 4 <= end) {                      // 4-wide step
            const int s0 = csr[e + g];
            float x0, x1, x2, x3;
            loadrow(s0, x0, x1, x2, x3);
            a0 += x0; a1 += x1; a2 += x2; a3 += x3;
            e += 4;
        }
        const int rem = end - e;                 // 0..3 tail, one per group
        if (g < rem) {
            const int s0 = csr[e + g];
            float x0, x1, x2, x3;
            loadrow(s0, x0, x1, x2, x3);
            c0 += x0; c1 += x1; c2 += x2; c3 += x3;
        }
        a0 += c0; a1 += c1; a2 += c2; a3 += c3;

        // cross-group reduce: groups hold same features at same gl
        #define RED(x) x += __shfl_xor(x, 16, 64); x += __shfl_xor(x, 32, 64);
        RED(a0) RED(a1) RED(a2) RED(a3)
        #undef RED

        float res = 0.f;
        const int deg = end - beg;
        if (deg > 0) {                           // wave-uniform
            const float inv = 1.f / (float)deg;
            float m[4] = {a0 * inv, a1 * inv, a2 * inv, a3 * inv};
            float acc = bj;
            #pragma unroll
            for (int k = 0; k < D; ++k)
                acc += __shfl(m[k & 3], k >> 2, 64) * w[k];
            res = fmaxf(acc, 0.f);
        }
        out[(size_t)node * D + lane] = res;
    }
}

// ---------------------------------------------------------------------------
// ws layout (ints): cnt[N] | cursor[N] | offs[N+1..pad64] | bsums[256] |
//                   csr[E] | hb[N*D bf16 = N*D/2 ints]   (~20.4 MB)
// ---------------------------------------------------------------------------
extern "C" void kernel_launch(void* const* d_in, const int* in_sizes, int n_in,
                              void* d_out, int out_size, void* d_ws, size_t ws_size,
                              hipStream_t stream) {
    const float* h    = (const float*)d_in[0];
    const int*   esrc = (const int*)d_in[1];
    const int*   edst = (const int*)d_in[2];
    const float* W    = (const float*)d_in[3];
    const float* b    = (const float*)d_in[4];

    const int N  = in_sizes[0] / D;
    const int E  = in_sizes[1];
    const int E4 = E >> 2;
    const int nb = (N + CHUNK - 1) / CHUNK;

    float* out = (float*)d_out;

    int* wsI    = (int*)d_ws;
    int* cnt    = wsI;                       // [N]
    int* cursor = wsI + N;                   // [N]
    int* offs   = wsI + 2 * N;               // [N+1]
    int* bsums  = wsI + 3 * N + 64;          // [<=256]
    int* csr    = wsI + 3 * N + 64 + 256;    // [E]
    unsigned short* hb = (unsigned short*)(csr + E);   // [N*D] bf16

    const size_t need = ((size_t)(3 * N + 64 + 256 + E) + (size_t)N * D / 2)
                        * sizeof(int);
    const bool useBf16 = (ws_size >= need);

    hipMemsetAsync(cnt, 0, (size_t)2 * N * sizeof(int), stream);

    if (useBf16)
        cvt_kernel<<<1024, 256, 0, stream>>>(
            (const float4*)h, (ushort4*)hb, N * D / 4);

    hist_kernel<<<1024, 256, 0, stream>>>(
        (const int4*)edst, edst, cnt, E4, E);
    scan_chunks_kernel<<<nb, 256, 0, stream>>>(cnt, offs, bsums, N);
    scan_bsums_kernel<<<1, 256, 0, stream>>>(bsums, nb, offs, N, E);
    scan_add_kernel<<<(N + 255) / 256, 256, 0, stream>>>(offs, bsums, N);
    fill_csr_kernel<<<1024, 256, 0, stream>>>(
        (const int4*)esrc, (const int4*)edst, esrc, edst,
        offs, cursor, csr, E4, E);

    if (useBf16)
        gather_gemm_kernel<true><<<4096, 256, 0, stream>>>(
            hb, csr, offs, W, b, out, N);
    else
        gather_gemm_kernel<false><<<4096, 256, 0, stream>>>(
            h, csr, offs, W, b, out, N);
}

// Round 5
// 225.311 us; speedup vs baseline: 2.5590x; 1.5989x over previous
//
#include <hip/hip_runtime.h>

#define D 64

typedef __attribute__((ext_vector_type(8))) short bf16x8;
typedef __attribute__((ext_vector_type(4))) float f32x4;

__device__ __forceinline__ unsigned short f2bf(float x) {
    unsigned int u = __float_as_uint(x);
    u += 0x7FFFu + ((u >> 16) & 1u);     // RNE
    return (unsigned short)(u >> 16);
}
__device__ __forceinline__ float bf2f(unsigned short v) {
    return __uint_as_float((unsigned int)v << 16);
}

// ---------------------------------------------------------------------------
// prep: blocks [0,cvtBlocks) convert W (and optionally h) to bf16;
//       blocks [cvtBlocks, grid) build the ELL table in ONE edge pass:
//       pos = atomicAdd(cnt[dst]); ell[dst*stride + pos] = src.
// ---------------------------------------------------------------------------
__global__ __launch_bounds__(256) void prep_kernel(
    const float4* __restrict__ h4, ushort4* __restrict__ hb4, int nh4,
    const float4* __restrict__ W4, ushort4* __restrict__ Wb4, int nw4,
    const int4* __restrict__ esrc4, const int4* __restrict__ edst4,
    const int* __restrict__ esrc, const int* __restrict__ edst,
    int* __restrict__ cnt, int* __restrict__ ell, int stride_,
    int E4, int E, int cvtBlocks)
{
    if ((int)blockIdx.x < cvtBlocks) {
        const int tid = blockIdx.x * blockDim.x + threadIdx.x;
        const int gsz = cvtBlocks * blockDim.x;
        for (int i = tid; i < nw4; i += gsz) {          // W -> bf16 (1024 it)
            const float4 f = W4[i];
            ushort4 o;
            o.x = f2bf(f.x); o.y = f2bf(f.y); o.z = f2bf(f.z); o.w = f2bf(f.w);
            Wb4[i] = o;
        }
        for (int i = tid; i < nh4; i += gsz) {          // h -> bf16
            const float4 f = h4[i];
            ushort4 o;
            o.x = f2bf(f.x); o.y = f2bf(f.y); o.z = f2bf(f.z); o.w = f2bf(f.w);
            hb4[i] = o;
        }
    } else {
        const int tid = (blockIdx.x - cvtBlocks) * blockDim.x + threadIdx.x;
        const int gsz = (gridDim.x - cvtBlocks) * blockDim.x;
        for (int i = tid; i < E4; i += gsz) {
            const int4 s = esrc4[i];
            const int4 d = edst4[i];
            int p;
            p = atomicAdd(&cnt[d.x], 1); if (p < stride_) ell[(size_t)d.x * stride_ + p] = s.x;
            p = atomicAdd(&cnt[d.y], 1); if (p < stride_) ell[(size_t)d.y * stride_ + p] = s.y;
            p = atomicAdd(&cnt[d.z], 1); if (p < stride_) ell[(size_t)d.z * stride_ + p] = s.z;
            p = atomicAdd(&cnt[d.w], 1); if (p < stride_) ell[(size_t)d.w * stride_ + p] = s.w;
        }
        if (tid == 0)
            for (int e = E4 * 4; e < E; ++e) {
                const int dd = edst[e];
                const int p = atomicAdd(&cnt[dd], 1);
                if (p < stride_) ell[(size_t)dd * stride_ + p] = esrc[e];
            }
    }
}

// ---------------------------------------------------------------------------
// gather: wave = 4 groups x 16 lanes; group g owns node quad*4+g entirely.
// Lane gl covers features 4*gl..4*gl+3 (8B bf16 / 16B f32 per row-load).
// 16-iteration inner loop, all loads independent -> up to 16 rows in
// flight per group (64/wave). Writes fp32 mean rows into `means` (=d_out).
// ---------------------------------------------------------------------------
template <bool BF16H>
__global__ __launch_bounds__(256) void gather_kernel(
    const void* __restrict__ hsrc,
    const int* __restrict__ ell,
    const int* __restrict__ cnt,
    float* __restrict__ means,
    int stride_, int N)
{
    const int lane = threadIdx.x & 63;
    const int g    = lane >> 4;
    const int gl   = lane & 15;

    const int quad = (blockIdx.x * blockDim.x + threadIdx.x) >> 6;
    const int node = quad * 4 + g;
    if (node >= N) return;

    const unsigned short* __restrict__ hb = (const unsigned short*)hsrc;
    const float*          __restrict__ hf = (const float*)hsrc;

    const int degT = cnt[node];                 // true degree (group-uniform)
    const int deg  = min(degT, stride_);
    const size_t rowbase = (size_t)node * stride_;

    float a0 = 0.f, a1 = 0.f, a2 = 0.f, a3 = 0.f;

    for (int c = 0; c < deg; c += 16) {
        // coalesced 64B per group; slots >= deg are garbage but in-bounds
        const int sgl = ell[rowbase + c + gl];
        const int rem = deg - c;                // group-uniform
        #pragma unroll
        for (int j = 0; j < 16; ++j) {
            if (j < rem) {                      // group-uniform condition
                const int s = __shfl(sgl, j, 16);
                if (BF16H) {
                    const ushort4 v = *(const ushort4*)(hb + (size_t)s * D + gl * 4);
                    a0 += bf2f(v.x); a1 += bf2f(v.y);
                    a2 += bf2f(v.z); a3 += bf2f(v.w);
                } else {
                    const float4 v = *(const float4*)(hf + (size_t)s * D + gl * 4);
                    a0 += v.x; a1 += v.y; a2 += v.z; a3 += v.w;
                }
            }
        }
    }

    const float inv = (degT > 0) ? 1.f / (float)degT : 0.f;
    float4 m;
    m.x = a0 * inv; m.y = a1 * inv; m.z = a2 * inv; m.w = a3 * inv;
    *(float4*)(means + (size_t)node * D + gl * 4) = m;
}

// ---------------------------------------------------------------------------
// gemm: out[n][j] = relu(mean[n][:] . W[j][:] + b[j]), masked to 0 if deg==0.
// One 16-row tile per wave, in place on d_out (wave reads ONLY its own 16
// rows into registers before storing -> no hazard). mfma_f32_16x16x32_bf16:
//   A-frag: lane holds row (l&15), k = (l>>4)*8..+7   (contiguous 8 bf16)
//   B-frag: lane holds col (l&15), k = (l>>4)*8..+7   = Wb row (col), contig
//   C/D   : col = l&15, row = (l>>4)*4 + reg           [m89-verified]
// ---------------------------------------------------------------------------
__global__ __launch_bounds__(256) void gemm_kernel(
    float* __restrict__ inout,                  // means in, result out
    const unsigned short* __restrict__ Wb,
    const float* __restrict__ bias,
    const int* __restrict__ cnt,
    int N)
{
    const int lane = threadIdx.x & 63;
    const int wv   = (blockIdx.x * blockDim.x + threadIdx.x) >> 6;
    const int n0   = wv * 16;
    if (n0 >= N) return;

    const int r16 = lane & 15;
    const int kq  = lane >> 4;

    int arow = n0 + r16;
    if (arow >= N) arow = N - 1;                // benign clamp (N%16==0 here)

    // A-frags: fp32 means -> bf16, 8 elems per k-step
    bf16x8 afr[2];
    #pragma unroll
    for (int ks = 0; ks < 2; ++ks) {
        const float* ap = inout + (size_t)arow * D + ks * 32 + kq * 8;
        const float4 f0 = *(const float4*)ap;
        const float4 f1 = *(const float4*)(ap + 4);
        bf16x8 a;
        a[0] = (short)f2bf(f0.x); a[1] = (short)f2bf(f0.y);
        a[2] = (short)f2bf(f0.z); a[3] = (short)f2bf(f0.w);
        a[4] = (short)f2bf(f1.x); a[5] = (short)f2bf(f1.y);
        a[6] = (short)f2bf(f1.z); a[7] = (short)f2bf(f1.w);
        afr[ks] = a;
    }

    // degree mask for the 4 rows this lane stores
    int dmask[4];
    #pragma unroll
    for (int r = 0; r < 4; ++r) {
        const int node = n0 + kq * 4 + r;
        dmask[r] = (node < N) ? cnt[node] : 0;
    }

    #pragma unroll
    for (int cb = 0; cb < 4; ++cb) {
        const unsigned short* wp = Wb + (size_t)(cb * 16 + r16) * D + kq * 8;
        const bf16x8 b0 = *(const bf16x8*)wp;          // k 0..31 chunk
        const bf16x8 b1 = *(const bf16x8*)(wp + 32);   // k 32..63 chunk
        f32x4 acc = {0.f, 0.f, 0.f, 0.f};
        acc = __builtin_amdgcn_mfma_f32_16x16x32_bf16(afr[0], b0, acc, 0, 0, 0);
        acc = __builtin_amdgcn_mfma_f32_16x16x32_bf16(afr[1], b1, acc, 0, 0, 0);

        const float bb = bias[cb * 16 + r16];
        #pragma unroll
        for (int r = 0; r < 4; ++r) {
            const int node = n0 + kq * 4 + r;
            if (node < N) {
                const float val = acc[r] + bb;
                inout[(size_t)node * D + cb * 16 + r16] =
                    (dmask[r] > 0) ? fmaxf(val, 0.f) : 0.f;
            }
        }
    }
}

// ---------------------------------------------------------------------------
// ws layout: cnt[N] | ell[N*stride] | Wb[D*D bf16] | hb[N*D bf16, optional]
// means lives in d_out (fp32), overwritten in place by gemm.
// ---------------------------------------------------------------------------
extern "C" void kernel_launch(void* const* d_in, const int* in_sizes, int n_in,
                              void* d_out, int out_size, void* d_ws, size_t ws_size,
                              hipStream_t stream) {
    const float* h    = (const float*)d_in[0];
    const int*   esrc = (const int*)d_in[1];
    const int*   edst = (const int*)d_in[2];
    const float* W    = (const float*)d_in[3];
    const float* b    = (const float*)d_in[4];

    const int N  = in_sizes[0] / D;
    const int E  = in_sizes[1];
    const int E4 = E >> 2;

    float* out = (float*)d_out;

    // choose (stride, bf16-h) by available workspace
    const size_t wbB = (size_t)D * D * 2;      // 8 KB
    const size_t hbB = (size_t)N * D * 2;      // 12.8 MB
    auto need = [&](int st, bool bf) {
        return (size_t)N * 4 + (size_t)N * st * 4 + wbB + (bf ? hbB : 0);
    };
    int  stride_ = 64; bool useBf16 = true;
    if      (ws_size >= need(64, true))  { stride_ = 64; useBf16 = true;  }
    else if (ws_size >= need(48, true))  { stride_ = 48; useBf16 = true;  }
    else if (ws_size >= need(64, false)) { stride_ = 64; useBf16 = false; }
    else if (ws_size >= need(48, false)) { stride_ = 48; useBf16 = false; }
    else                                 { stride_ = 32; useBf16 = false; }

    int*            cnt = (int*)d_ws;                          // [N]
    int*            ell = cnt + N;                             // [N*stride]
    unsigned short* Wb  = (unsigned short*)(ell + (size_t)N * stride_); // [D*D]
    unsigned short* hb  = Wb + (size_t)D * D;                  // [N*D] opt

    hipMemsetAsync(cnt, 0, (size_t)N * sizeof(int), stream);

    const int cvtBlocks = 2048, buildBlocks = 1024;
    prep_kernel<<<cvtBlocks + buildBlocks, 256, 0, stream>>>(
        (const float4*)h, (ushort4*)hb, useBf16 ? N * D / 4 : 0,
        (const float4*)W, (ushort4*)Wb, D * D / 4,
        (const int4*)esrc, (const int4*)edst, esrc, edst,
        cnt, ell, stride_, E4, E, cvtBlocks);

    const int quads = (N + 3) / 4;
    const int gBlocks = (quads + 3) / 4;       // 4 waves/block, 1 quad/wave
    if (useBf16)
        gather_kernel<true><<<gBlocks, 256, 0, stream>>>(
            hb, ell, cnt, out, stride_, N);
    else
        gather_kernel<false><<<gBlocks, 256, 0, stream>>>(
            h, ell, cnt, out, stride_, N);

    const int tiles = (N + 15) / 16;
    gemm_kernel<<<(tiles + 3) / 4, 256, 0, stream>>>(out, Wb, b, cnt, N);
}